// Round 5
// baseline (778.096 us; speedup 1.0000x reference)
//
#include <hip/hip_runtime.h>

// ScaledDotProductAttention: B=2,H=16,S=2048,DK=DV=64, fp32 in/out, mask (True => -1e9).
// R5: single-barrier pipelined K-loop — double-buffered K/V tiles (glds it+1 issued
//     right after the barrier that drains tile it) + mask prefetched one iter ahead
//     into registers (nontemporal), so the per-iter vmcnt(0) drain waits on loads
//     issued a full iteration earlier. 64-q blocks, grid 1024, 3 blocks/CU.

#define LOG2E 1.4426950408889634f
#define QSCALE (0.125f * LOG2E)          // fold 1/sqrt(64) and log2(e) into Q

typedef __attribute__((ext_vector_type(8))) short short8;   // 8 x bf16
typedef __attribute__((ext_vector_type(4))) short short4v;  // 4 x bf16
typedef __attribute__((ext_vector_type(4))) float f32x4;    // MFMA acc
typedef unsigned __attribute__((ext_vector_type(4))) uintv4;

constexpr int S = 2048, D = 64;

__device__ __forceinline__ short bf16rne(float x) {
  union { float f; unsigned u; } cv; cv.f = x;
  unsigned u = cv.u;
  u += 0x7fffu + ((u >> 16) & 1u);
  return (short)(u >> 16);
}

__device__ __forceinline__ void glds16(const void* g, void* l) {
  __builtin_amdgcn_global_load_lds(
      (const __attribute__((address_space(1))) void*)g,
      (__attribute__((address_space(3))) void*)l, 16, 0, 0);
}

// Merged prep: blocks [0,2048) convert K fp32->bf16; [2048,3072) build bf16 V^T.
// Block 0 wave 0 additionally detects mask format: 1 = byte-packed, 0 = 4-byte elems.
__global__ void prep(const float* __restrict__ kp, const float* __restrict__ vp,
                     short* __restrict__ kb, short* __restrict__ vt,
                     const unsigned* __restrict__ m, int* __restrict__ flag) {
  const int b = blockIdx.x;
  const int tid = threadIdx.x;
  if (b == 0 && tid < 64) {
    unsigned v = m[tid];
    unsigned long long big = __ballot(v > 1u && v != 0x3F800000u);
    unsigned long long isf = __ballot(v == 0x3F800000u);
    if (tid == 0) *flag = (big != 0ull && isf == 0ull) ? 1 : 0;
  }
  if (b < 2048) {
    size_t i = ((size_t)b * 256 + tid) * 8;
    float4 a = *(const float4*)(kp + i);
    float4 c = *(const float4*)(kp + i + 4);
    short8 s;
    s[0] = bf16rne(a.x); s[1] = bf16rne(a.y); s[2] = bf16rne(a.z); s[3] = bf16rne(a.w);
    s[4] = bf16rne(c.x); s[5] = bf16rne(c.y); s[6] = bf16rne(c.z); s[7] = bf16rne(c.w);
    *(short8*)&kb[i] = s;
  } else {
    __shared__ float tile[64][65];
    const int bb = b - 2048;
    const int bh = bb >> 5, k0 = (bb & 31) * 64;
    const float* src = vp + ((size_t)(bh * S + k0)) * D;
#pragma unroll
    for (int i = 0; i < 4; ++i) {
      int row = i * 16 + (tid >> 4);
      int col = (tid & 15) * 4;
      float4 x = *(const float4*)(src + row * D + col);
      tile[row][col] = x.x; tile[row][col + 1] = x.y;
      tile[row][col + 2] = x.z; tile[row][col + 3] = x.w;
    }
    __syncthreads();
#pragma unroll
    for (int i = 0; i < 4; ++i) {
      int dim = i * 16 + (tid >> 4);
      int kb4 = (tid & 15) * 4;
      short4v s;
#pragma unroll
      for (int j = 0; j < 4; ++j) s[j] = bf16rne(tile[kb4 + j][dim]);
      *(short4v*)&vt[((size_t)(bh * D + dim)) * S + k0 + kb4] = s;
    }
  }
}

__launch_bounds__(256, 3)
__global__ void attn_fwd(const float* __restrict__ qp, const short* __restrict__ kb,
                         const short* __restrict__ vt, const void* __restrict__ mp,
                         float* __restrict__ op, const int* __restrict__ fmtp) {
  const int fmt  = *fmtp;
  const int tid  = threadIdx.x;
  const int lane = tid & 63;
  const int w    = tid >> 6;          // wave 0..3
  const int c    = lane & 15;
  const int quad = lane >> 4;

  const int bh = blockIdx.x >> 5;
  const int q0 = (blockIdx.x & 31) * 64;

  __shared__ short ks[2][64 * 64];    // K tile [key][dim], chunk-xor-swizzled, dbuf
  __shared__ short vs[2][64 * 64];    // V^T tile [dim][key], chunk-xor-swizzled, dbuf
  __shared__ short pst[4][16 * 72];   // per-wave P [q][key], +8 pad

  // ---- Q B-fragments: lane n=c is q-row q0+w*16+c ----
  const float* qg = qp + ((size_t)(bh * S + q0 + w * 16 + c)) * D;
  short8 qB[2];
#pragma unroll
  for (int kk = 0; kk < 2; ++kk) {
    const float* p = qg + kk * 32 + quad * 8;
    float4 x = *(const float4*)(p);
    float4 y = *(const float4*)(p + 4);
    short8 f;
    f[0] = bf16rne(x.x * QSCALE); f[1] = bf16rne(x.y * QSCALE);
    f[2] = bf16rne(x.z * QSCALE); f[3] = bf16rne(x.w * QSCALE);
    f[4] = bf16rne(y.x * QSCALE); f[5] = bf16rne(y.y * QSCALE);
    f[6] = bf16rne(y.z * QSCALE); f[7] = bf16rne(y.w * QSCALE);
    qB[kk] = f;
  }

  f32x4 O[4];
#pragma unroll
  for (int t = 0; t < 4; ++t) O[t] = (f32x4){0.f, 0.f, 0.f, 0.f};
  float L = 0.f;

  // staging geometry: slot=(h2*4+w)*64+lane; row=(h2*4+w)*8+(lane>>3)
  const int rsub = lane >> 3;
  const int csw  = (lane & 7) ^ rsub;                 // swizzled source chunk
  const short* kbase = kb + ((size_t)(bh * S)) * D;
  const short* vbase = vt + ((size_t)(bh * D)) * S;

  const int sw0 = ((quad    ) ^ (c & 7)) * 8;
  const int sw1 = ((quad | 4) ^ (c & 7)) * 8;

  const size_t mrow = ((size_t)(bh * S + q0 + w * 16 + c)) * S;

  uintv4  mr4[4];                     // int32-format raw prefetch
  unsigned mr1[4];                    // uint8-format raw prefetch

  // ---- issue tile 0 + mask 0 ----
#pragma unroll
  for (int h2 = 0; h2 < 2; ++h2) {
    const int row = (h2 * 4 + w) * 8 + rsub;
    glds16(kbase + (size_t)row * 64 + csw * 8, (char*)&ks[0][0] + (h2 * 4 + w) * 1024);
    glds16(vbase + (size_t)row * S + csw * 8,  (char*)&vs[0][0] + (h2 * 4 + w) * 1024);
  }
  if (fmt == 1) {
    const unsigned char* mq = (const unsigned char*)mp + mrow + 4 * quad;
#pragma unroll
    for (int t = 0; t < 4; ++t)
      mr1[t] = __builtin_nontemporal_load((const unsigned*)(mq + 16 * t));
  } else {
    const uintv4* mq = (const uintv4*)((const unsigned*)mp + mrow + 4 * quad);
#pragma unroll
    for (int t = 0; t < 4; ++t)
      mr4[t] = __builtin_nontemporal_load(mq + 4 * t);
  }

  for (int it = 0; it < 32; ++it) {
    const int cur = it & 1;
    __syncthreads();                  // drains tile(it) + mask(it), issued one iter ago

    // ---- unpack mask regs (byte r of mb[t] = masked(key=16t+4quad+r)) ----
    unsigned mb[4];
    if (fmt == 1) {
#pragma unroll
      for (int t = 0; t < 4; ++t) mb[t] = mr1[t];
    } else {
#pragma unroll
      for (int t = 0; t < 4; ++t) {
        uintv4 v = mr4[t];
        mb[t] = (v[0] ? 1u : 0u) | (v[1] ? 0x100u : 0u) |
                (v[2] ? 0x10000u : 0u) | (v[3] ? 0x1000000u : 0u);
      }
    }

    // ---- issue tile(it+1) + mask(it+1); drained at NEXT barrier ----
    if (it + 1 < 32) {
      const int k1 = (it + 1) * 64;
#pragma unroll
      for (int h2 = 0; h2 < 2; ++h2) {
        const int row = (h2 * 4 + w) * 8 + rsub;
        glds16(kbase + (size_t)(k1 + row) * 64 + csw * 8,
               (char*)&ks[cur ^ 1][0] + (h2 * 4 + w) * 1024);
        glds16(vbase + (size_t)row * S + k1 + csw * 8,
               (char*)&vs[cur ^ 1][0] + (h2 * 4 + w) * 1024);
      }
      if (fmt == 1) {
        const unsigned char* mq = (const unsigned char*)mp + mrow + k1 + 4 * quad;
#pragma unroll
        for (int t = 0; t < 4; ++t)
          mr1[t] = __builtin_nontemporal_load((const unsigned*)(mq + 16 * t));
      } else {
        const uintv4* mq = (const uintv4*)((const unsigned*)mp + mrow + k1 + 4 * quad);
#pragma unroll
        for (int t = 0; t < 4; ++t)
          mr4[t] = __builtin_nontemporal_load(mq + 4 * t);
      }
    }

    // ---- Sc^T = K*Q^T: lane(quad,c): q=c, key=16t+4quad+r ----
    float part = 0.f;
#pragma unroll
    for (int t = 0; t < 4; ++t) {
      short8 ka0 = *(const short8*)&ks[cur][(16 * t + c) * 64 + sw0];
      short8 ka1 = *(const short8*)&ks[cur][(16 * t + c) * 64 + sw1];
      f32x4 z = (f32x4){0.f, 0.f, 0.f, 0.f};
      z = __builtin_amdgcn_mfma_f32_16x16x32_bf16(ka0, qB[0], z, 0, 0, 0);
      z = __builtin_amdgcn_mfma_f32_16x16x32_bf16(ka1, qB[1], z, 0, 0, 0);
      short4v s4;
#pragma unroll
      for (int r = 0; r < 4; ++r) {
        float e = ((mb[t] >> (8 * r)) & 0xffu) ? 0.f : exp2f(z[r]);
        part += e;
        s4[r] = bf16rne(e);
      }
      *(short4v*)&pst[w][c * 72 + 16 * t + 4 * quad] = s4;
    }

    part += __shfl_xor(part, 16);
    part += __shfl_xor(part, 32);
    L += part;

    // ---- O += P*V ----
    short8 pa0 = *(const short8*)&pst[w][c * 72 + quad * 8];
    short8 pa1 = *(const short8*)&pst[w][c * 72 + 32 + quad * 8];
#pragma unroll
    for (int t = 0; t < 4; ++t) {
      short8 vb0 = *(const short8*)&vs[cur][(16 * t + c) * 64 + sw0];
      short8 vb1 = *(const short8*)&vs[cur][(16 * t + c) * 64 + sw1];
      O[t] = __builtin_amdgcn_mfma_f32_16x16x32_bf16(pa0, vb0, O[t], 0, 0, 0);
      O[t] = __builtin_amdgcn_mfma_f32_16x16x32_bf16(pa1, vb1, O[t], 0, 0, 0);
    }
  }

  // ---- epilogue: O[m=q=quad*4+r][n=dim=16t+c] / L(q) ----
#pragma unroll
  for (int r = 0; r < 4; ++r) {
    float Lr = __shfl(L, (lane & 48) | (quad * 4 + r));
    float inv = 1.f / Lr;
    const size_t ob = ((size_t)(bh * S + q0 + w * 16 + quad * 4 + r)) * D;
#pragma unroll
    for (int t = 0; t < 4; ++t) op[ob + 16 * t + c] = O[t][r] * inv;
  }
}

extern "C" void kernel_launch(void* const* d_in, const int* in_sizes, int n_in,
                              void* d_out, int out_size, void* d_ws, size_t ws_size,
                              hipStream_t stream) {
  const float* q = (const float*)d_in[0];
  const float* k = (const float*)d_in[1];
  const float* v = (const float*)d_in[2];
  const void*  m = d_in[3];

  short* kbuf = (short*)d_ws;                         // 8 MiB bf16 K
  short* vtb  = (short*)((char*)d_ws + (8u << 20));   // 8 MiB bf16 V^T
  int* flag   = (int*)((char*)d_ws + (16u << 20));

  prep<<<3072, 256, 0, stream>>>(k, v, kbuf, vtb, (const unsigned*)m, flag);
  attn_fwd<<<1024, 256, 0, stream>>>(q, kbuf, vtb, m, (float*)d_out, flag);
}

// Round 7
// 748.745 us; speedup vs baseline: 1.0392x; 1.0392x over previous
//
#include <hip/hip_runtime.h>

// ScaledDotProductAttention: B=2,H=16,S=2048,DK=DV=64, fp32 in/out, mask (True => -1e9).
// R7 = R3 (proven): single-buffered glds K/V tiles, 64-q blocks, grid 1024, 4 blocks/CU,
//     transposed-score flash (lane owns one q-column), no-max softmax (exp2 direct)
//   + R5's validated mask register prefetch: mask(it+1) issued after barrier 2 (during
//     compute), nontemporal — its vmcnt drain lands at the NEXT iteration's barrier 1,
//     so barrier 2 waits only on the L2-warm glds tile loads.

#define LOG2E 1.4426950408889634f
#define QSCALE (0.125f * LOG2E)          // fold 1/sqrt(64) and log2(e) into Q

typedef __attribute__((ext_vector_type(8))) short short8;   // 8 x bf16
typedef __attribute__((ext_vector_type(4))) short short4v;  // 4 x bf16
typedef __attribute__((ext_vector_type(4))) float f32x4;    // MFMA acc
typedef unsigned __attribute__((ext_vector_type(4))) uintv4;

constexpr int S = 2048, D = 64;

__device__ __forceinline__ short bf16rne(float x) {
  union { float f; unsigned u; } cv; cv.f = x;
  unsigned u = cv.u;
  u += 0x7fffu + ((u >> 16) & 1u);
  return (short)(u >> 16);
}

__device__ __forceinline__ void glds16(const void* g, void* l) {
  __builtin_amdgcn_global_load_lds(
      (const __attribute__((address_space(1))) void*)g,
      (__attribute__((address_space(3))) void*)l, 16, 0, 0);
}

// Merged prep: blocks [0,2048) convert K fp32->bf16; [2048,3072) build bf16 V^T.
// Block 0 wave 0 additionally detects mask format: 1 = byte-packed, 0 = 4-byte elems.
__global__ void prep(const float* __restrict__ kp, const float* __restrict__ vp,
                     short* __restrict__ kb, short* __restrict__ vt,
                     const unsigned* __restrict__ m, int* __restrict__ flag) {
  const int b = blockIdx.x;
  const int tid = threadIdx.x;
  if (b == 0 && tid < 64) {
    unsigned v = m[tid];
    unsigned long long big = __ballot(v > 1u && v != 0x3F800000u);
    unsigned long long isf = __ballot(v == 0x3F800000u);
    if (tid == 0) *flag = (big != 0ull && isf == 0ull) ? 1 : 0;
  }
  if (b < 2048) {
    size_t i = ((size_t)b * 256 + tid) * 8;
    float4 a = *(const float4*)(kp + i);
    float4 c = *(const float4*)(kp + i + 4);
    short8 s;
    s[0] = bf16rne(a.x); s[1] = bf16rne(a.y); s[2] = bf16rne(a.z); s[3] = bf16rne(a.w);
    s[4] = bf16rne(c.x); s[5] = bf16rne(c.y); s[6] = bf16rne(c.z); s[7] = bf16rne(c.w);
    *(short8*)&kb[i] = s;
  } else {
    __shared__ float tile[64][65];
    const int bb = b - 2048;
    const int bh = bb >> 5, k0 = (bb & 31) * 64;
    const float* src = vp + ((size_t)(bh * S + k0)) * D;
#pragma unroll
    for (int i = 0; i < 4; ++i) {
      int row = i * 16 + (tid >> 4);
      int col = (tid & 15) * 4;
      float4 x = *(const float4*)(src + row * D + col);
      tile[row][col] = x.x; tile[row][col + 1] = x.y;
      tile[row][col + 2] = x.z; tile[row][col + 3] = x.w;
    }
    __syncthreads();
#pragma unroll
    for (int i = 0; i < 4; ++i) {
      int dim = i * 16 + (tid >> 4);
      int kb4 = (tid & 15) * 4;
      short4v s;
#pragma unroll
      for (int j = 0; j < 4; ++j) s[j] = bf16rne(tile[kb4 + j][dim]);
      *(short4v*)&vt[((size_t)(bh * D + dim)) * S + k0 + kb4] = s;
    }
  }
}

__launch_bounds__(256, 4)
__global__ void attn_fwd(const float* __restrict__ qp, const short* __restrict__ kb,
                         const short* __restrict__ vt, const void* __restrict__ mp,
                         float* __restrict__ op, const int* __restrict__ fmtp) {
  const int fmt  = *fmtp;
  const int tid  = threadIdx.x;
  const int lane = tid & 63;
  const int w    = tid >> 6;          // wave 0..3
  const int c    = lane & 15;
  const int quad = lane >> 4;

  const int bh = blockIdx.x >> 5;
  const int q0 = (blockIdx.x & 31) * 64;

  __shared__ short ks[64 * 64];       // K tile [key][dim], chunk-xor-swizzled
  __shared__ short vs[64 * 64];       // V^T tile [dim][key], chunk-xor-swizzled
  __shared__ short pst[4][16 * 72];   // per-wave P [q][key], +8 pad

  // ---- Q B-fragments: lane n=c is q-row q0+w*16+c ----
  const float* qg = qp + ((size_t)(bh * S + q0 + w * 16 + c)) * D;
  short8 qB[2];
#pragma unroll
  for (int kk = 0; kk < 2; ++kk) {
    const float* p = qg + kk * 32 + quad * 8;
    float4 x = *(const float4*)(p);
    float4 y = *(const float4*)(p + 4);
    short8 f;
    f[0] = bf16rne(x.x * QSCALE); f[1] = bf16rne(x.y * QSCALE);
    f[2] = bf16rne(x.z * QSCALE); f[3] = bf16rne(x.w * QSCALE);
    f[4] = bf16rne(y.x * QSCALE); f[5] = bf16rne(y.y * QSCALE);
    f[6] = bf16rne(y.z * QSCALE); f[7] = bf16rne(y.w * QSCALE);
    qB[kk] = f;
  }

  f32x4 O[4];
#pragma unroll
  for (int t = 0; t < 4; ++t) O[t] = (f32x4){0.f, 0.f, 0.f, 0.f};
  float L = 0.f;

  // staging geometry: slot=(h2*4+w)*64+lane; row=(h2*4+w)*8+(lane>>3)
  const int rsub = lane >> 3;
  const int csw  = (lane & 7) ^ rsub;                 // swizzled source chunk
  const short* kbase = kb + ((size_t)(bh * S)) * D;
  const short* vbase = vt + ((size_t)(bh * D)) * S;

  const int sw0 = ((quad    ) ^ (c & 7)) * 8;
  const int sw1 = ((quad | 4) ^ (c & 7)) * 8;

  const size_t mrow = ((size_t)(bh * S + q0 + w * 16 + c)) * S;

  uintv4  mr4[4];                     // int32-format mask prefetch regs
  unsigned mr1[4];                    // uint8-format mask prefetch regs

  // ---- prologue: issue mask(0) loads ----
  if (fmt == 1) {
    const unsigned char* mq = (const unsigned char*)mp + mrow + 4 * quad;
#pragma unroll
    for (int t = 0; t < 4; ++t)
      mr1[t] = __builtin_nontemporal_load((const unsigned*)(mq + 16 * t));
  } else {
    const unsigned* mq = (const unsigned*)mp + mrow + 4 * quad;
#pragma unroll
    for (int t = 0; t < 4; ++t)
      mr4[t] = __builtin_nontemporal_load((const uintv4*)(mq + 16 * t));
  }

  for (int it = 0; it < 32; ++it) {
    const int k0 = it * 64;
    __syncthreads();                  // bar1: prev-iter LDS reads done; mask(it) drained

    // ---- async stage K and V^T tiles (bf16, direct to LDS) ----
#pragma unroll
    for (int h2 = 0; h2 < 2; ++h2) {
      const int row = (h2 * 4 + w) * 8 + rsub;
      glds16(kbase + (size_t)(k0 + row) * 64 + csw * 8,
             (char*)ks + (h2 * 4 + w) * 1024);
      glds16(vbase + (size_t)row * S + k0 + csw * 8,
             (char*)vs + (h2 * 4 + w) * 1024);
    }
    __syncthreads();                  // bar2: drains glds (L2-warm) only

    // ---- unpack mask(it) from regs (byte r of mb[t] = masked(key=16t+4quad+r)) ----
    unsigned mb[4];
    if (fmt == 1) {
#pragma unroll
      for (int t = 0; t < 4; ++t) mb[t] = mr1[t];
    } else {
#pragma unroll
      for (int t = 0; t < 4; ++t) {
        uintv4 v = mr4[t];
        mb[t] = (v[0] ? 1u : 0u) | (v[1] ? 0x100u : 0u) |
                (v[2] ? 0x10000u : 0u) | (v[3] ? 0x1000000u : 0u);
      }
    }

    // ---- issue mask(it+1); drains at next iteration's bar1 ----
    if (it + 1 < 32) {
      const int k1 = (it + 1) * 64;
      if (fmt == 1) {
        const unsigned char* mq = (const unsigned char*)mp + mrow + k1 + 4 * quad;
#pragma unroll
        for (int t = 0; t < 4; ++t)
          mr1[t] = __builtin_nontemporal_load((const unsigned*)(mq + 16 * t));
      } else {
        const unsigned* mq = (const unsigned*)mp + mrow + k1 + 4 * quad;
#pragma unroll
        for (int t = 0; t < 4; ++t)
          mr4[t] = __builtin_nontemporal_load((const uintv4*)(mq + 16 * t));
      }
    }

    // ---- Sc^T = K*Q^T: lane(quad,c): q=c, key=16t+4quad+r ----
    float part = 0.f;
#pragma unroll
    for (int t = 0; t < 4; ++t) {
      short8 ka0 = *(const short8*)&ks[(16 * t + c) * 64 + sw0];
      short8 ka1 = *(const short8*)&ks[(16 * t + c) * 64 + sw1];
      f32x4 z = (f32x4){0.f, 0.f, 0.f, 0.f};
      z = __builtin_amdgcn_mfma_f32_16x16x32_bf16(ka0, qB[0], z, 0, 0, 0);
      z = __builtin_amdgcn_mfma_f32_16x16x32_bf16(ka1, qB[1], z, 0, 0, 0);
      short4v s4;
#pragma unroll
      for (int r = 0; r < 4; ++r) {
        float e = ((mb[t] >> (8 * r)) & 0xffu) ? 0.f : exp2f(z[r]);
        part += e;
        s4[r] = bf16rne(e);
      }
      *(short4v*)&pst[w][c * 72 + 16 * t + 4 * quad] = s4;
    }

    part += __shfl_xor(part, 16);
    part += __shfl_xor(part, 32);
    L += part;

    // ---- O += P*V ----
    short8 pa0 = *(const short8*)&pst[w][c * 72 + quad * 8];
    short8 pa1 = *(const short8*)&pst[w][c * 72 + 32 + quad * 8];
#pragma unroll
    for (int t = 0; t < 4; ++t) {
      short8 vb0 = *(const short8*)&vs[(16 * t + c) * 64 + sw0];
      short8 vb1 = *(const short8*)&vs[(16 * t + c) * 64 + sw1];
      O[t] = __builtin_amdgcn_mfma_f32_16x16x32_bf16(pa0, vb0, O[t], 0, 0, 0);
      O[t] = __builtin_amdgcn_mfma_f32_16x16x32_bf16(pa1, vb1, O[t], 0, 0, 0);
    }
  }

  // ---- epilogue: O[m=q=quad*4+r][n=dim=16t+c] / L(q) ----
#pragma unroll
  for (int r = 0; r < 4; ++r) {
    float Lr = __shfl(L, (lane & 48) | (quad * 4 + r));
    float inv = 1.f / Lr;
    const size_t ob = ((size_t)(bh * S + q0 + w * 16 + quad * 4 + r)) * D;
#pragma unroll
    for (int t = 0; t < 4; ++t) op[ob + 16 * t + c] = O[t][r] * inv;
  }
}

extern "C" void kernel_launch(void* const* d_in, const int* in_sizes, int n_in,
                              void* d_out, int out_size, void* d_ws, size_t ws_size,
                              hipStream_t stream) {
  const float* q = (const float*)d_in[0];
  const float* k = (const float*)d_in[1];
  const float* v = (const float*)d_in[2];
  const void*  m = d_in[3];

  short* kbuf = (short*)d_ws;                         // 8 MiB bf16 K
  short* vtb  = (short*)((char*)d_ws + (8u << 20));   // 8 MiB bf16 V^T
  int* flag   = (int*)((char*)d_ws + (16u << 20));

  prep<<<3072, 256, 0, stream>>>(k, v, kbuf, vtb, (const unsigned*)m, flag);
  attn_fwd<<<1024, 256, 0, stream>>>(q, kbuf, vtb, m, (float*)d_out, flag);
}